// Round 1
// baseline (924.906 us; speedup 1.0000x reference)
//
#include <hip/hip_runtime.h>

#define FIN 512
#define FMID 16
#define FOUT 64

// ============================ CSR build ============================

__global__ void k_count(const int* __restrict__ dst, int* __restrict__ cnt, int E) {
  int e = blockIdx.x * blockDim.x + threadIdx.x;
  if (e < E) atomicAdd(&cnt[dst[e]], 1);
}

// per-256-chunk sums for the hierarchical exclusive scan
__global__ __launch_bounds__(256) void k_blocksum(const int* __restrict__ cnt,
                                                  int* __restrict__ bsum, int n) {
  __shared__ int sm[4];
  int i = blockIdx.x * 256 + threadIdx.x;
  int v = (i < n) ? cnt[i] : 0;
#pragma unroll
  for (int off = 32; off >= 1; off >>= 1) v += __shfl_xor(v, off);
  if ((threadIdx.x & 63) == 0) sm[threadIdx.x >> 6] = v;
  __syncthreads();
  if (threadIdx.x == 0) bsum[blockIdx.x] = sm[0] + sm[1] + sm[2] + sm[3];
}

// single-block exclusive scan of the (<=512) chunk sums
__global__ __launch_bounds__(512) void k_scanb(int* __restrict__ bsum, int nb) {
  __shared__ int sm[512];
  int t = threadIdx.x;
  int v = (t < nb) ? bsum[t] : 0;
  sm[t] = v;
  __syncthreads();
  for (int off = 1; off < 512; off <<= 1) {
    int add = (t >= off) ? sm[t - off] : 0;
    __syncthreads();
    sm[t] += add;
    __syncthreads();
  }
  if (t < nb) bsum[t] = sm[t] - v;  // exclusive
}

// per-chunk exclusive scan + chunk offset -> rowstart[N+1]
__global__ __launch_bounds__(256) void k_scanf(const int* __restrict__ cnt,
                                               const int* __restrict__ bsum,
                                               int* __restrict__ rowstart, int n) {
  __shared__ int sm[256];
  int t = threadIdx.x;
  int i = blockIdx.x * 256 + t;
  int v = (i < n) ? cnt[i] : 0;
  sm[t] = v;
  __syncthreads();
  for (int off = 1; off < 256; off <<= 1) {
    int add = (t >= off) ? sm[t - off] : 0;
    __syncthreads();
    sm[t] += add;
    __syncthreads();
  }
  int excl = sm[t] - v + bsum[blockIdx.x];
  if (i < n) rowstart[i] = excl;
  if (i == n - 1) rowstart[n] = excl + v;  // total = E
}

__global__ void k_dis(const int* __restrict__ cnt, float* __restrict__ dis, int n) {
  int i = blockIdx.x * blockDim.x + threadIdx.x;
  if (i < n) dis[i] = rsqrtf((float)cnt[i] + 1.0f);  // +1 self-loop
}

__global__ void k_scatter(const int* __restrict__ src, const int* __restrict__ dst,
                          int* __restrict__ cur, int* __restrict__ csr_src, int E) {
  int e = blockIdx.x * blockDim.x + threadIdx.x;
  if (e < E) {
    int p = atomicAdd(&cur[dst[e]], 1);
    csr_src[p] = src[e];
  }
}

// ============================ dense layers ============================

// hs[node, 0:16] = (x[node, 0:512] @ W1) * dis[node]. One wave per node:
// lane = q*16+j, quarter q covers k in [q*128, q*128+128), lane j accumulates
// output j. W1 staged in LDS; 4-way bank conflict on w reads (1.58x, acceptable).
__global__ __launch_bounds__(256) void k_gemm1(const float* __restrict__ x,
                                               const float* __restrict__ W1,
                                               const float* __restrict__ dis,
                                               float* __restrict__ hs, int n) {
  __shared__ float w[FIN * FMID];  // 32 KB
  for (int idx = threadIdx.x; idx < FIN * FMID; idx += 256) w[idx] = W1[idx];
  __syncthreads();
  const int lane = threadIdx.x & 63;
  const int q = lane >> 4, j = lane & 15;
  const int node = blockIdx.x * 4 + (threadIdx.x >> 6);
  if (node >= n) return;
  const float4* xr = (const float4*)(x + (size_t)node * FIN + q * 128);
  float acc = 0.f;
#pragma unroll
  for (int t4 = 0; t4 < 32; ++t4) {
    float4 xv = xr[t4];
    int k = q * 128 + t4 * 4;
    acc += xv.x * w[(k + 0) * FMID + j];
    acc += xv.y * w[(k + 1) * FMID + j];
    acc += xv.z * w[(k + 2) * FMID + j];
    acc += xv.w * w[(k + 3) * FMID + j];
  }
  acc += __shfl_xor(acc, 16);
  acc += __shfl_xor(acc, 32);
  if (lane < FMID) hs[(size_t)node * FMID + j] = acc * dis[node];
}

// CSR gather propagation. 16 lanes per node, lane j owns feature j.
// Input hs is pre-scaled by dis[src], so:
//   raw[d][j] = dis[d] * (hs[d][j] + sum_{s in N(d)} hs[s][j])
// RELU=true (layer 1): out = relu(raw + bias) * dis[d]   (pre-scaled for layer 2)
// RELU=false (layer 2): out = raw                        (k_out adds b2)
template <bool RELU>
__global__ __launch_bounds__(256) void k_prop_csr(const float* __restrict__ hs,
                                                  const int* __restrict__ rowstart,
                                                  const int* __restrict__ csr,
                                                  const float* __restrict__ dis,
                                                  const float* __restrict__ bias,
                                                  float* __restrict__ outp, int n) {
  int t = blockIdx.x * blockDim.x + threadIdx.x;
  int node = t >> 4;
  if (node >= n) return;
  int j = t & 15;
  int beg = rowstart[node], end = rowstart[node + 1];
  float s = hs[node * FMID + j];  // self-loop term (already dis-scaled)
  int i = beg;
  int stop = beg + ((end - beg) & ~15);
  // batches of 16: one coalesced index load, then 16 independent row gathers
  for (; i < stop; i += 16) {
    int sv = csr[i + j];
#pragma unroll
    for (int u = 0; u < 16; ++u) {
      int sidx = __shfl(sv, u, 16);
      s += hs[sidx * FMID + j];
    }
  }
  if (i < end) {
    int rem = end - i;
    int sv = (i + j < end) ? csr[i + j] : 0;
    for (int u = 0; u < rem; ++u) {
      int sidx = __shfl(sv, u, 16);
      s += hs[sidx * FMID + j];
    }
  }
  float dd = dis[node];
  float v = dd * s;
  if (RELU) v = fmaxf(v + bias[j], 0.f) * dd;
  outp[node * FMID + j] = v;
}

// out[node, 0:64] = log_softmax(a2[node, 0:16] @ W2 + b2). One wave per node.
__global__ __launch_bounds__(256) void k_out(const float* __restrict__ a2,
                                             const float* __restrict__ W2,
                                             const float* __restrict__ b2,
                                             float* __restrict__ out, int n) {
  __shared__ float w[FMID * FOUT];  // 4 KB
  for (int idx = threadIdx.x; idx < FMID * FOUT; idx += 256) w[idx] = W2[idx];
  __syncthreads();
  const int lane = threadIdx.x & 63;
  const int node = blockIdx.x * 4 + (threadIdx.x >> 6);
  if (node >= n) return;
  const float* ar = a2 + (size_t)node * FMID;
  float o = b2[lane];
#pragma unroll
  for (int k = 0; k < FMID; ++k) o += ar[k] * w[k * FOUT + lane];
  float m = o;
#pragma unroll
  for (int off = 32; off >= 1; off >>= 1) m = fmaxf(m, __shfl_xor(m, off));
  float e = __expf(o - m);
  float s = e;
#pragma unroll
  for (int off = 32; off >= 1; off >>= 1) s += __shfl_xor(s, off);
  out[(size_t)node * FOUT + lane] = o - m - __logf(s);
}

// ==================== fallback (atomic path, small ws) ====================

__global__ void k_deg_init(float* __restrict__ deg, int n) {
  int i = blockIdx.x * blockDim.x + threadIdx.x;
  if (i < n) deg[i] = 1.0f;
}
__global__ void k_deg_edges(const int* __restrict__ dst, float* __restrict__ deg, int E) {
  int e = blockIdx.x * blockDim.x + threadIdx.x;
  if (e < E) atomicAdd(&deg[dst[e]], 1.0f);
}
__global__ void k_deg_finish(float* __restrict__ deg, int n) {
  int i = blockIdx.x * blockDim.x + threadIdx.x;
  if (i < n) deg[i] = rsqrtf(deg[i]);
}
// a[d] = hs[d] * dis[d]  (self-loop; hs already carries one dis factor)
__global__ void k_selfloop_s(const float* __restrict__ hs, const float* __restrict__ dis,
                             float* __restrict__ a, int total16) {
  int t = blockIdx.x * blockDim.x + threadIdx.x;
  if (t < total16) a[t] = hs[t] * dis[t >> 4];
}
// a[d] += hs[s] * dis[d]
__global__ void k_prop_atomic(const float* __restrict__ hs, const int* __restrict__ src,
                              const int* __restrict__ dst, const float* __restrict__ dis,
                              float* __restrict__ outp, int E) {
  int t = blockIdx.x * blockDim.x + threadIdx.x;
  int e = t >> 4;
  if (e >= E) return;
  int jj = t & 15;
  int s = src[e], d = dst[e];
  atomicAdd(&outp[(size_t)d * FMID + jj], hs[(size_t)s * FMID + jj] * dis[d]);
}
// layer-1 epilogue: relu(a + b) * dis  (pre-scaled for layer 2)
__global__ void k_bias_relu_s(float* __restrict__ a, const float* __restrict__ b,
                              const float* __restrict__ dis, int total16) {
  int t = blockIdx.x * blockDim.x + threadIdx.x;
  if (t < total16) {
    float v = a[t] + b[t & 15];
    a[t] = (v > 0.f ? v : 0.f) * dis[t >> 4];
  }
}

// ============================ launcher ============================

extern "C" void kernel_launch(void* const* d_in, const int* in_sizes, int n_in,
                              void* d_out, int out_size, void* d_ws, size_t ws_size,
                              hipStream_t stream) {
  const float* x  = (const float*)d_in[0];
  const int* edge = (const int*)d_in[1];
  const float* W1 = (const float*)d_in[2];
  const float* b1 = (const float*)d_in[3];
  const float* W2 = (const float*)d_in[4];
  const float* b2 = (const float*)d_in[5];
  float* out = (float*)d_out;

  const int N = in_sizes[0] / FIN;   // 100000
  const int E = in_sizes[1] / 2;     // 3200000
  const int* src = edge;
  const int* dst = edge + E;

  const int T = 256;
  const int t16n = N * FMID;

  // CSR-path workspace: floats dis[N] | buf0[16N] | buf1[16N], then ints
  // cnt[N] | rowstart[N+1] | cur[N] | bsum[512] | csr[E]  (~27 MB)
  size_t need_csr = ((size_t)33 * N + (size_t)3 * N + 1 + 512 + (size_t)E) * 4;

  if (ws_size >= need_csr) {
    float* fbase = (float*)d_ws;
    float* dis  = fbase;
    float* buf0 = fbase + (size_t)N;         // hs, later a2
    float* buf1 = fbase + 17 * (size_t)N;    // a1 (scaled)
    int* ibase    = (int*)(fbase + 33 * (size_t)N);
    int* cnt      = ibase;
    int* rowstart = ibase + N;
    int* cur      = ibase + 2 * (size_t)N + 1;
    int* bsum     = ibase + 3 * (size_t)N + 1;
    int* csr      = ibase + 3 * (size_t)N + 1 + 512;

    const int NB = (N + 255) / 256;  // 391 <= 512

    hipMemsetAsync(cnt, 0, (size_t)N * sizeof(int), stream);
    k_count   <<<(E + T - 1) / T, T, 0, stream>>>(dst, cnt, E);
    k_blocksum<<<NB, 256, 0, stream>>>(cnt, bsum, N);
    k_scanb   <<<1, 512, 0, stream>>>(bsum, NB);
    k_scanf   <<<NB, 256, 0, stream>>>(cnt, bsum, rowstart, N);
    k_dis     <<<(N + T - 1) / T, T, 0, stream>>>(cnt, dis, N);
    hipMemcpyAsync(cur, rowstart, (size_t)N * sizeof(int),
                   hipMemcpyDeviceToDevice, stream);
    k_scatter <<<(E + T - 1) / T, T, 0, stream>>>(src, dst, cur, csr, E);

    k_gemm1   <<<(N + 3) / 4, T, 0, stream>>>(x, W1, dis, buf0, N);

    const int PB = (t16n + T - 1) / T;
    k_prop_csr<true>  <<<PB, T, 0, stream>>>(buf0, rowstart, csr, dis, b1, buf1, N);
    k_prop_csr<false> <<<PB, T, 0, stream>>>(buf1, rowstart, csr, dis, b1, buf0, N);
    k_out     <<<(N + 3) / 4, T, 0, stream>>>(buf0, W2, b2, out, N);
  } else {
    // atomic fallback: dis[N] | hs[16N] | a1[16N] | a2[16N] (~19.6 MB)
    float* f   = (float*)d_ws;
    float* dis = f;
    float* hs  = f + (size_t)N;
    float* a1  = f + 17 * (size_t)N;
    float* a2  = f + 33 * (size_t)N;
    const long te = (long)E * FMID;

    k_deg_init  <<<(N + T - 1) / T, T, 0, stream>>>(dis, N);
    k_deg_edges <<<(E + T - 1) / T, T, 0, stream>>>(dst, dis, E);
    k_deg_finish<<<(N + T - 1) / T, T, 0, stream>>>(dis, N);

    k_gemm1     <<<(N + 3) / 4, T, 0, stream>>>(x, W1, dis, hs, N);

    k_selfloop_s<<<(t16n + T - 1) / T, T, 0, stream>>>(hs, dis, a1, t16n);
    k_prop_atomic<<<(int)((te + T - 1) / T), T, 0, stream>>>(hs, src, dst, dis, a1, E);
    k_bias_relu_s<<<(t16n + T - 1) / T, T, 0, stream>>>(a1, b1, dis, t16n);

    k_selfloop_s<<<(t16n + T - 1) / T, T, 0, stream>>>(a1, dis, a2, t16n);
    k_prop_atomic<<<(int)((te + T - 1) / T), T, 0, stream>>>(a1, src, dst, dis, a2, E);

    k_out       <<<(N + 3) / 4, T, 0, stream>>>(a2, W2, b2, out, N);
  }
}

// Round 2
// 760.995 us; speedup vs baseline: 1.2154x; 1.2154x over previous
//
#include <hip/hip_runtime.h>

#define FIN 512
#define FMID 16
#define FOUT 64

// ============================ CSR build ============================

// Count in-degree AND record each edge's rank among same-dst edges.
// rank[e] = position of edge e within dst[e]'s CSR segment (any order ok).
// 4 edges per thread for ILP (4 independent atomic chains in flight).
__global__ void k_count(const int* __restrict__ dst, int* __restrict__ cnt,
                        int* __restrict__ rank, int E) {
  int t = blockIdx.x * blockDim.x + threadIdx.x;
  int e = t * 4;
  if (e + 3 < E) {
    int4 d = *(const int4*)(dst + e);
    int r0 = atomicAdd(&cnt[d.x], 1);
    int r1 = atomicAdd(&cnt[d.y], 1);
    int r2 = atomicAdd(&cnt[d.z], 1);
    int r3 = atomicAdd(&cnt[d.w], 1);
    *(int4*)(rank + e) = make_int4(r0, r1, r2, r3);
  } else {
    for (; e < E; ++e) rank[e] = atomicAdd(&cnt[dst[e]], 1);
  }
}

// per-256-chunk sums for the hierarchical exclusive scan
__global__ __launch_bounds__(256) void k_blocksum(const int* __restrict__ cnt,
                                                  int* __restrict__ bsum, int n) {
  __shared__ int sm[4];
  int i = blockIdx.x * 256 + threadIdx.x;
  int v = (i < n) ? cnt[i] : 0;
#pragma unroll
  for (int off = 32; off >= 1; off >>= 1) v += __shfl_xor(v, off);
  if ((threadIdx.x & 63) == 0) sm[threadIdx.x >> 6] = v;
  __syncthreads();
  if (threadIdx.x == 0) bsum[blockIdx.x] = sm[0] + sm[1] + sm[2] + sm[3];
}

// single-block exclusive scan of the (<=512) chunk sums
__global__ __launch_bounds__(512) void k_scanb(int* __restrict__ bsum, int nb) {
  __shared__ int sm[512];
  int t = threadIdx.x;
  int v = (t < nb) ? bsum[t] : 0;
  sm[t] = v;
  __syncthreads();
  for (int off = 1; off < 512; off <<= 1) {
    int add = (t >= off) ? sm[t - off] : 0;
    __syncthreads();
    sm[t] += add;
    __syncthreads();
  }
  if (t < nb) bsum[t] = sm[t] - v;  // exclusive
}

// per-chunk exclusive scan + chunk offset -> rowstart[N+1]; also dis = rsqrt(deg+1)
__global__ __launch_bounds__(256) void k_scanf(const int* __restrict__ cnt,
                                               const int* __restrict__ bsum,
                                               int* __restrict__ rowstart,
                                               float* __restrict__ dis, int n) {
  __shared__ int sm[256];
  int t = threadIdx.x;
  int i = blockIdx.x * 256 + t;
  int v = (i < n) ? cnt[i] : 0;
  sm[t] = v;
  __syncthreads();
  for (int off = 1; off < 256; off <<= 1) {
    int add = (t >= off) ? sm[t - off] : 0;
    __syncthreads();
    sm[t] += add;
    __syncthreads();
  }
  int excl = sm[t] - v + bsum[blockIdx.x];
  if (i < n) {
    rowstart[i] = excl;
    dis[i] = rsqrtf((float)v + 1.0f);  // +1 self-loop
  }
  if (i == n - 1) rowstart[n] = excl + v;  // total = E
}

// Atomic-free scatter: position is rowstart[dst] + rank. Pure stores, no RMW.
__global__ void k_scatter(const int* __restrict__ src, const int* __restrict__ dst,
                          const int* __restrict__ rank, const int* __restrict__ rowstart,
                          int* __restrict__ csr_src, int E) {
  int t = blockIdx.x * blockDim.x + threadIdx.x;
  int e = t * 4;
  if (e + 3 < E) {
    int4 s = *(const int4*)(src + e);
    int4 d = *(const int4*)(dst + e);
    int4 r = *(const int4*)(rank + e);
    int p0 = rowstart[d.x] + r.x;
    int p1 = rowstart[d.y] + r.y;
    int p2 = rowstart[d.z] + r.z;
    int p3 = rowstart[d.w] + r.w;
    csr_src[p0] = s.x;
    csr_src[p1] = s.y;
    csr_src[p2] = s.z;
    csr_src[p3] = s.w;
  } else {
    for (; e < E; ++e) csr_src[rowstart[dst[e]] + rank[e]] = src[e];
  }
}

// ============================ dense layers ============================

// hs[node, 0:16] = (x[node, 0:512] @ W1) * dis[node]. One wave per node:
// lane = q*16+j, quarter q covers k in [q*128, q*128+128), lane j accumulates
// output j. W1 staged in LDS; 4-way bank conflict on w reads (1.58x, acceptable).
__global__ __launch_bounds__(256) void k_gemm1(const float* __restrict__ x,
                                               const float* __restrict__ W1,
                                               const float* __restrict__ dis,
                                               float* __restrict__ hs, int n) {
  __shared__ float w[FIN * FMID];  // 32 KB
  for (int idx = threadIdx.x; idx < FIN * FMID; idx += 256) w[idx] = W1[idx];
  __syncthreads();
  const int lane = threadIdx.x & 63;
  const int q = lane >> 4, j = lane & 15;
  const int node = blockIdx.x * 4 + (threadIdx.x >> 6);
  if (node >= n) return;
  const float4* xr = (const float4*)(x + (size_t)node * FIN + q * 128);
  float acc = 0.f;
#pragma unroll
  for (int t4 = 0; t4 < 32; ++t4) {
    float4 xv = xr[t4];
    int k = q * 128 + t4 * 4;
    acc += xv.x * w[(k + 0) * FMID + j];
    acc += xv.y * w[(k + 1) * FMID + j];
    acc += xv.z * w[(k + 2) * FMID + j];
    acc += xv.w * w[(k + 3) * FMID + j];
  }
  acc += __shfl_xor(acc, 16);
  acc += __shfl_xor(acc, 32);
  if (lane < FMID) hs[(size_t)node * FMID + j] = acc * dis[node];
}

// CSR gather propagation, float4 rows. 16 lanes per node, split into 4
// subgroups of 4 lanes; subgroup g handles edge slot g, lane-in-subgroup c
// owns features [4c, 4c+4). Per 16-edge batch: one coalesced index load,
// then 16 float4 row-gathers (4 per lane). End: reduce across subgroups.
// Input hs is pre-scaled by dis[src]:
//   raw[d][j] = dis[d] * (hs[d][j] + sum_{s in N(d)} hs[s][j])
// RELU=true (layer 1): out = relu(raw + bias) * dis[d]   (pre-scaled for layer 2)
// RELU=false (layer 2): out = raw                        (k_out adds b2)
template <bool RELU>
__global__ __launch_bounds__(256) void k_prop_csr(const float* __restrict__ hs,
                                                  const int* __restrict__ rowstart,
                                                  const int* __restrict__ csr,
                                                  const float* __restrict__ dis,
                                                  const float* __restrict__ bias,
                                                  float* __restrict__ outp, int n) {
  int t = blockIdx.x * blockDim.x + threadIdx.x;
  int node = t >> 4;
  if (node >= n) return;
  const int j = t & 15;   // lane within 16-group
  const int g = j >> 2;   // subgroup (edge slot)
  const int c = j & 3;    // float4 column
  int beg = rowstart[node], end = rowstart[node + 1];
  float4 acc = make_float4(0.f, 0.f, 0.f, 0.f);
  if (g == 0) {  // self-loop term (already dis[src]-scaled)
    float4 v = ((const float4*)(hs + (size_t)node * FMID))[c];
    acc.x += v.x; acc.y += v.y; acc.z += v.z; acc.w += v.w;
  }
  int i = beg;
  int stop = beg + ((end - beg) & ~15);
  for (; i < stop; i += 16) {
    int sv = csr[i + j];
#pragma unroll
    for (int k = 0; k < 4; ++k) {
      int sidx = __shfl(sv, k * 4 + g, 16);
      float4 v = ((const float4*)(hs + (size_t)sidx * FMID))[c];
      acc.x += v.x; acc.y += v.y; acc.z += v.z; acc.w += v.w;
    }
  }
  // remainder: one edge per step, round-robin over subgroups
  for (int u = 0; i < end; ++i, ++u) {
    int sidx = csr[i];  // uniform within group -> broadcast
    if (g == (u & 3)) {
      float4 v = ((const float4*)(hs + (size_t)sidx * FMID))[c];
      acc.x += v.x; acc.y += v.y; acc.z += v.z; acc.w += v.w;
    }
  }
  // reduce across subgroups (lanes differing in bits 2..3)
#pragma unroll
  for (int off = 4; off <= 8; off <<= 1) {
    acc.x += __shfl_xor(acc.x, off, 16);
    acc.y += __shfl_xor(acc.y, off, 16);
    acc.z += __shfl_xor(acc.z, off, 16);
    acc.w += __shfl_xor(acc.w, off, 16);
  }
  if (g == 0) {
    float dd = dis[node];
    float4 r;
    r.x = dd * acc.x; r.y = dd * acc.y; r.z = dd * acc.z; r.w = dd * acc.w;
    if (RELU) {
      float4 bb = ((const float4*)bias)[c];
      r.x = fmaxf(r.x + bb.x, 0.f) * dd;
      r.y = fmaxf(r.y + bb.y, 0.f) * dd;
      r.z = fmaxf(r.z + bb.z, 0.f) * dd;
      r.w = fmaxf(r.w + bb.w, 0.f) * dd;
    }
    ((float4*)(outp + (size_t)node * FMID))[c] = r;
  }
}

// out[node, 0:64] = log_softmax(a2[node, 0:16] @ W2 + b2). One wave per node.
__global__ __launch_bounds__(256) void k_out(const float* __restrict__ a2,
                                             const float* __restrict__ W2,
                                             const float* __restrict__ b2,
                                             float* __restrict__ out, int n) {
  __shared__ float w[FMID * FOUT];  // 4 KB
  for (int idx = threadIdx.x; idx < FMID * FOUT; idx += 256) w[idx] = W2[idx];
  __syncthreads();
  const int lane = threadIdx.x & 63;
  const int node = blockIdx.x * 4 + (threadIdx.x >> 6);
  if (node >= n) return;
  const float* ar = a2 + (size_t)node * FMID;
  float o = b2[lane];
#pragma unroll
  for (int k = 0; k < FMID; ++k) o += ar[k] * w[k * FOUT + lane];
  float m = o;
#pragma unroll
  for (int off = 32; off >= 1; off >>= 1) m = fmaxf(m, __shfl_xor(m, off));
  float e = __expf(o - m);
  float s = e;
#pragma unroll
  for (int off = 32; off >= 1; off >>= 1) s += __shfl_xor(s, off);
  out[(size_t)node * FOUT + lane] = o - m - __logf(s);
}

// ==================== fallback (atomic path, small ws) ====================

__global__ void k_deg_init(float* __restrict__ deg, int n) {
  int i = blockIdx.x * blockDim.x + threadIdx.x;
  if (i < n) deg[i] = 1.0f;
}
__global__ void k_deg_edges(const int* __restrict__ dst, float* __restrict__ deg, int E) {
  int e = blockIdx.x * blockDim.x + threadIdx.x;
  if (e < E) atomicAdd(&deg[dst[e]], 1.0f);
}
__global__ void k_deg_finish(float* __restrict__ deg, int n) {
  int i = blockIdx.x * blockDim.x + threadIdx.x;
  if (i < n) deg[i] = rsqrtf(deg[i]);
}
__global__ void k_selfloop_s(const float* __restrict__ hs, const float* __restrict__ dis,
                             float* __restrict__ a, int total16) {
  int t = blockIdx.x * blockDim.x + threadIdx.x;
  if (t < total16) a[t] = hs[t] * dis[t >> 4];
}
__global__ void k_prop_atomic(const float* __restrict__ hs, const int* __restrict__ src,
                              const int* __restrict__ dst, const float* __restrict__ dis,
                              float* __restrict__ outp, int E) {
  int t = blockIdx.x * blockDim.x + threadIdx.x;
  int e = t >> 4;
  if (e >= E) return;
  int jj = t & 15;
  int s = src[e], d = dst[e];
  atomicAdd(&outp[(size_t)d * FMID + jj], hs[(size_t)s * FMID + jj] * dis[d]);
}
__global__ void k_bias_relu_s(float* __restrict__ a, const float* __restrict__ b,
                              const float* __restrict__ dis, int total16) {
  int t = blockIdx.x * blockDim.x + threadIdx.x;
  if (t < total16) {
    float v = a[t] + b[t & 15];
    a[t] = (v > 0.f ? v : 0.f) * dis[t >> 4];
  }
}

// ============================ launcher ============================

extern "C" void kernel_launch(void* const* d_in, const int* in_sizes, int n_in,
                              void* d_out, int out_size, void* d_ws, size_t ws_size,
                              hipStream_t stream) {
  const float* x  = (const float*)d_in[0];
  const int* edge = (const int*)d_in[1];
  const float* W1 = (const float*)d_in[2];
  const float* b1 = (const float*)d_in[3];
  const float* W2 = (const float*)d_in[4];
  const float* b2 = (const float*)d_in[5];
  float* out = (float*)d_out;

  const int N = in_sizes[0] / FIN;   // 100000
  const int E = in_sizes[1] / 2;     // 3200000
  const int* src = edge;
  const int* dst = edge + E;

  const int T = 256;
  const int t16n = N * FMID;

  // CSR-path workspace: floats dis[N] | buf0[16N] | buf1[16N], then ints
  // cnt[N] | rowstart[N+1] | (unused N) | bsum[512] | csr[E]  (~27 MB)
  // rank[E] aliases buf0..buf1 (32N floats == E ints); dead before k_gemm1.
  size_t need_csr = ((size_t)33 * N + (size_t)3 * N + 1 + 512 + (size_t)E) * 4;

  if (ws_size >= need_csr) {
    float* fbase = (float*)d_ws;
    float* dis  = fbase;
    float* buf0 = fbase + (size_t)N;         // hs, later a2
    float* buf1 = fbase + 17 * (size_t)N;    // a1 (scaled)
    int* rank     = (int*)(fbase + (size_t)N);  // aliases buf0+buf1 (E ints)
    int* ibase    = (int*)(fbase + 33 * (size_t)N);
    int* cnt      = ibase;
    int* rowstart = ibase + N;
    int* bsum     = ibase + 3 * (size_t)N + 1;
    int* csr      = ibase + 3 * (size_t)N + 1 + 512;

    const int NB = (N + 255) / 256;  // 391 <= 512

    hipMemsetAsync(cnt, 0, (size_t)N * sizeof(int), stream);
    k_count   <<<(E / 4 + T - 1) / T, T, 0, stream>>>(dst, cnt, rank, E);
    k_blocksum<<<NB, 256, 0, stream>>>(cnt, bsum, N);
    k_scanb   <<<1, 512, 0, stream>>>(bsum, NB);
    k_scanf   <<<NB, 256, 0, stream>>>(cnt, bsum, rowstart, dis, N);
    k_scatter <<<(E / 4 + T - 1) / T, T, 0, stream>>>(src, dst, rank, rowstart, csr, E);

    k_gemm1   <<<(N + 3) / 4, T, 0, stream>>>(x, W1, dis, buf0, N);

    const int PB = (t16n + T - 1) / T;
    k_prop_csr<true>  <<<PB, T, 0, stream>>>(buf0, rowstart, csr, dis, b1, buf1, N);
    k_prop_csr<false> <<<PB, T, 0, stream>>>(buf1, rowstart, csr, dis, b1, buf0, N);
    k_out     <<<(N + 3) / 4, T, 0, stream>>>(buf0, W2, b2, out, N);
  } else {
    // atomic fallback: dis[N] | hs[16N] | a1[16N] | a2[16N] (~19.6 MB)
    float* f   = (float*)d_ws;
    float* dis = f;
    float* hs  = f + (size_t)N;
    float* a1  = f + 17 * (size_t)N;
    float* a2  = f + 33 * (size_t)N;
    const long te = (long)E * FMID;

    k_deg_init  <<<(N + T - 1) / T, T, 0, stream>>>(dis, N);
    k_deg_edges <<<(E + T - 1) / T, T, 0, stream>>>(dst, dis, E);
    k_deg_finish<<<(N + T - 1) / T, T, 0, stream>>>(dis, N);

    k_gemm1     <<<(N + 3) / 4, T, 0, stream>>>(x, W1, dis, hs, N);

    k_selfloop_s<<<(t16n + T - 1) / T, T, 0, stream>>>(hs, dis, a1, t16n);
    k_prop_atomic<<<(int)((te + T - 1) / T), T, 0, stream>>>(hs, src, dst, dis, a1, E);
    k_bias_relu_s<<<(t16n + T - 1) / T, T, 0, stream>>>(a1, b1, dis, t16n);

    k_selfloop_s<<<(t16n + T - 1) / T, T, 0, stream>>>(a1, dis, a2, t16n);
    k_prop_atomic<<<(int)((te + T - 1) / T), T, 0, stream>>>(a1, src, dst, dis, a2, E);

    k_out       <<<(N + 3) / 4, T, 0, stream>>>(a2, W2, b2, out, N);
  }
}